// Round 1
// baseline (6243.032 us; speedup 1.0000x reference)
//
#include <hip/hip_runtime.h>

#define Bdim 512
#define Tt   256
#define Ii   128
#define Hh   512
#define BM   16     // batch rows per group
#define NGRP 32
#define NSL  8      // column slices (WGs) per group

typedef __attribute__((ext_vector_type(4))) float f32x4;
typedef __attribute__((ext_vector_type(8))) short short8;

__device__ __forceinline__ unsigned short f2bf(float f) {
    unsigned u = __builtin_bit_cast(unsigned, f);
    u += 0x7fffu + ((u >> 16) & 1u);   // round-to-nearest-even
    return (unsigned short)(u >> 16);
}

__device__ __forceinline__ short8 pack_bf8(f32x4 lo, f32x4 hi) {
    short8 r;
    r[0] = (short)f2bf(lo[0]); r[1] = (short)f2bf(lo[1]);
    r[2] = (short)f2bf(lo[2]); r[3] = (short)f2bf(lo[3]);
    r[4] = (short)f2bf(hi[0]); r[5] = (short)f2bf(hi[1]);
    r[6] = (short)f2bf(hi[2]); r[7] = (short)f2bf(hi[3]);
    return r;
}

// weight fragment: B[k][n] = W[row][k], lane holds k = kbase..kbase+7 for its column
__device__ __forceinline__ short8 load_wfrag(const float* __restrict__ Whh,
                                             const float* __restrict__ Wih,
                                             int row, int k) {
    const float* p = (k < Hh) ? (Whh + row * Hh + k) : (Wih + row * Ii + (k - Hh));
    f32x4 lo = *(const f32x4*)p;
    f32x4 hi = *(const f32x4*)(p + 4);
    return pack_bf8(lo, hi);
}

__device__ __forceinline__ int ldsa(int row, int kbyte) {
    // XOR swizzle: spreads the stride-1280B rows across banks for ds_read_b128
    return (row * 1280 + kbyte) ^ ((row & 7) << 4);
}

__device__ __forceinline__ float sigm(float v)  { return 1.f / (1.f + __expf(-v)); }
__device__ __forceinline__ float tanhf_(float v){ return 1.f - 2.f / (__expf(2.f * v) + 1.f); }

__global__ void zero_ctr(int* c, int n) {
    int i = blockIdx.x * blockDim.x + threadIdx.x;
    if (i < n) c[i] = 0;
}

__global__ __launch_bounds__(256, 1)
void gru_persist(const float* __restrict__ x,   const float* __restrict__ Wih,
                 const float* __restrict__ Whh, const float* __restrict__ bih,
                 const float* __restrict__ bhh, const float* __restrict__ Wlin,
                 const float* __restrict__ blin, float* __restrict__ out,
                 float* __restrict__ hbuf, int* __restrict__ ctr)
{
    __shared__ __align__(16) unsigned char lA[16 * 1280];   // [16 rows][640 bf16]

    const int wg   = blockIdx.x;
    const int tid  = threadIdx.x;
    const int lane = tid & 63;
    const int w    = tid >> 6;          // wave 0..3
    // XCD-locality swizzle (perf heuristic only; bijective wg -> (g, sl))
    const int xcd = wg & 7, lg = (wg >> 3) & 3, sl = wg >> 5;
    const int g   = xcd * 4 + lg;       // group 0..31
    const int b0  = g * BM;
    const int jw  = sl * 64 + w * 16;   // this wave's 16 h-columns
    const int col16 = lane & 15;
    const int kg8   = (lane >> 4) * 8;  // k sub-offset within a K=32 tile
    const int colg  = jw + col16;       // global h-column this lane owns (D layout: col=lane&15)

    // biases (per-lane, per its column)
    const float br  = bih[colg] + bhh[colg];
    const float bz  = bih[Hh + colg] + bhh[Hh + colg];
    const float bxn = bih[2 * Hh + colg];
    const float bhn = bhh[2 * Hh + colg];

    // ---- load weight B-fragments once into registers (persistent) ----
    short8 wR[20], wZ[20], wN[20];
#pragma unroll
    for (int kt = 0; kt < 20; ++kt) {
        int k = kt * 32 + kg8;
        wR[kt] = load_wfrag(Whh, Wih, colg, k);
        wZ[kt] = load_wfrag(Whh, Wih, Hh + colg, k);
        wN[kt] = load_wfrag(Whh, Wih, 2 * Hh + colg, k);
    }

    float* hb0 = hbuf;
    float* hb1 = hbuf + Bdim * Hh;
    int* myctr = ctr + g * Tt;

    f32x4 hreg = {0.f, 0.f, 0.f, 0.f};  // own h tile, carried in fp32 across steps

#pragma unroll 1
    for (int t = 0; t < Tt; ++t) {
        const int pin = t & 1;
        float* hout = pin ? hb0 : hb1;
        const float* hin = pin ? hb1 : hb0;

        // ---- stage x_t (16 rows x 128) -> bf16 LDS cols [512,640) ----
#pragma unroll
        for (int it = 0; it < 2; ++it) {
            int idx = it * 256 + tid;      // [0,512): 512 float4 chunks
            int row = idx >> 5;            // 32 chunks per row
            int c4  = idx & 31;
            const f32x4 v = *(const f32x4*)(x + ((size_t)(b0 + row) * Tt + t) * Ii + c4 * 4);
            unsigned long long pk = (unsigned long long)f2bf(v[0])
                                  | ((unsigned long long)f2bf(v[1]) << 16)
                                  | ((unsigned long long)f2bf(v[2]) << 32)
                                  | ((unsigned long long)f2bf(v[3]) << 48);
            *(unsigned long long*)(lA + ldsa(row, 1024 + c4 * 8)) = pk;
        }
        __syncthreads();

        f32x4 accR = {0,0,0,0}, accZ = {0,0,0,0}, accNH = {0,0,0,0}, accNX = {0,0,0,0};

        // ---- x-part MFMAs (independent of h -> overlap with barrier wait) ----
#pragma unroll
        for (int kt = 16; kt < 20; ++kt) {
            short8 a = *(const short8*)(lA + ldsa(col16, (kt * 32 + kg8) * 2));
            accR  = __builtin_amdgcn_mfma_f32_16x16x32_bf16(a, wR[kt], accR, 0, 0, 0);
            accZ  = __builtin_amdgcn_mfma_f32_16x16x32_bf16(a, wZ[kt], accZ, 0, 0, 0);
            accNX = __builtin_amdgcn_mfma_f32_16x16x32_bf16(a, wN[kt], accNX, 0, 0, 0);
        }

        if (t > 0) {
            // ---- group barrier: wait for all 8 slices to finish step t-1 ----
            if (tid == 0) {
                while (__hip_atomic_load(myctr + (t - 1), __ATOMIC_ACQUIRE,
                                         __HIP_MEMORY_SCOPE_AGENT) < NSL)
                    __builtin_amdgcn_s_sleep(1);
            }
            __syncthreads();

            // ---- stage h panel (16 rows x 512 fp32) via coherent loads -> bf16 LDS ----
#pragma unroll
            for (int it = 0; it < 16; ++it) {
                int idx = it * 256 + tid;  // [0,4096): 8B chunks
                int row = idx >> 8;        // 256 chunks per row
                int c2  = idx & 255;
                unsigned long long vv = __hip_atomic_load(
                    (unsigned long long*)(hin + (size_t)(b0 + row) * Hh + c2 * 2),
                    __ATOMIC_RELAXED, __HIP_MEMORY_SCOPE_AGENT);
                float f0 = __builtin_bit_cast(float, (unsigned)(vv & 0xffffffffu));
                float f1 = __builtin_bit_cast(float, (unsigned)(vv >> 32));
                unsigned pk = (unsigned)f2bf(f0) | ((unsigned)f2bf(f1) << 16);
                *(unsigned*)(lA + ldsa(row, c2 * 4)) = pk;
            }
            __syncthreads();

            // ---- h-part MFMAs ----
#pragma unroll
            for (int kt = 0; kt < 16; ++kt) {
                short8 a = *(const short8*)(lA + ldsa(col16, (kt * 32 + kg8) * 2));
                accR  = __builtin_amdgcn_mfma_f32_16x16x32_bf16(a, wR[kt], accR, 0, 0, 0);
                accZ  = __builtin_amdgcn_mfma_f32_16x16x32_bf16(a, wZ[kt], accZ, 0, 0, 0);
                accNH = __builtin_amdgcn_mfma_f32_16x16x32_bf16(a, wN[kt], accNH, 0, 0, 0);
            }
        }

        // ---- gates + state update (C/D layout: col=lane&15, row=(lane>>4)*4+i) ----
#pragma unroll
        for (int i = 0; i < 4; ++i) {
            int row = (lane >> 4) * 4 + i;
            float hp = hreg[i];                       // own tile, exact fp32 carry
            float r  = sigm(accR[i] + br);
            float z  = sigm(accZ[i] + bz);
            float n  = tanhf_(accNX[i] + bxn + r * (accNH[i] + bhn));
            float hv = (1.f - z) * n + z * hp;
            hreg[i] = hv;
            __hip_atomic_store(hout + (size_t)(b0 + row) * Hh + colg, hv,
                               __ATOMIC_RELAXED, __HIP_MEMORY_SCOPE_AGENT);
        }
        __threadfence();
        __syncthreads();
        if (tid == 0)
            __hip_atomic_fetch_add(myctr + t, 1, __ATOMIC_RELEASE, __HIP_MEMORY_SCOPE_AGENT);
    }

    // ---- final linear: slice-0 WG of each group computes out[b0..b0+15] ----
    if (sl == 0) {
        if (tid == 0) {
            while (__hip_atomic_load(myctr + (Tt - 1), __ATOMIC_ACQUIRE,
                                     __HIP_MEMORY_SCOPE_AGENT) < NSL)
                __builtin_amdgcn_s_sleep(1);
        }
        __syncthreads();
        const float* hf = hb0;   // T even -> final state in buffer 0
        const float bl = blin[0];
        for (int rr = w; rr < BM; rr += 4) {
            int b = b0 + rr;
            float sum = 0.f;
#pragma unroll
            for (int c = 0; c < 4; ++c) {
                int cc = lane * 8 + c * 2;
                unsigned long long vv = __hip_atomic_load(
                    (unsigned long long*)(hf + (size_t)b * Hh + cc),
                    __ATOMIC_RELAXED, __HIP_MEMORY_SCOPE_AGENT);
                float f0 = __builtin_bit_cast(float, (unsigned)(vv & 0xffffffffu));
                float f1 = __builtin_bit_cast(float, (unsigned)(vv >> 32));
                sum += f0 * Wlin[cc] + f1 * Wlin[cc + 1];
            }
#pragma unroll
            for (int off = 32; off; off >>= 1) sum += __shfl_xor(sum, off);
            if (lane == 0) out[b] = sum + bl;
        }
    }
}

extern "C" void kernel_launch(void* const* d_in, const int* in_sizes, int n_in,
                              void* d_out, int out_size, void* d_ws, size_t ws_size,
                              hipStream_t stream) {
    const float* x    = (const float*)d_in[0];
    const float* Wih  = (const float*)d_in[1];
    const float* Whh  = (const float*)d_in[2];
    const float* bih  = (const float*)d_in[3];
    const float* bhh  = (const float*)d_in[4];
    const float* Wlin = (const float*)d_in[5];
    const float* blin = (const float*)d_in[6];
    float* out  = (float*)d_out;

    float* hbuf = (float*)d_ws;                                   // 2 * 512*512 fp32 = 2 MB
    int*   ctr  = (int*)((char*)d_ws + 2u * Bdim * Hh * sizeof(float));  // 32*256 ints

    zero_ctr<<<32, 256, 0, stream>>>(ctr, NGRP * Tt);
    gru_persist<<<256, 256, 0, stream>>>(x, Wih, Whh, bih, bhh, Wlin, blin, out, hbuf, ctr);
}

// Round 4
// 1388.535 us; speedup vs baseline: 4.4961x; 4.4961x over previous
//
#include <hip/hip_runtime.h>

#define Bdim 512
#define Tt   256
#define Ii   128
#define Hh   512
#define BM   16     // batch rows per group
#define NGRP 32
#define NSL  8      // column slices (WGs) per group

typedef __attribute__((ext_vector_type(4))) float f32x4;
typedef __attribute__((ext_vector_type(8))) short short8;

__device__ __forceinline__ unsigned short f2bf(float f) {
    unsigned u = __builtin_bit_cast(unsigned, f);
    u += 0x7fffu + ((u >> 16) & 1u);   // round-to-nearest-even
    return (unsigned short)(u >> 16);
}

__device__ __forceinline__ short8 pack_bf8(f32x4 lo, f32x4 hi) {
    short8 r;
    r[0] = (short)f2bf(lo[0]); r[1] = (short)f2bf(lo[1]);
    r[2] = (short)f2bf(lo[2]); r[3] = (short)f2bf(lo[3]);
    r[4] = (short)f2bf(hi[0]); r[5] = (short)f2bf(hi[1]);
    r[6] = (short)f2bf(hi[2]); r[7] = (short)f2bf(hi[3]);
    return r;
}

// weight fragment: B[k][n] = W[row][k], lane holds k = kbase..kbase+7 for its column
__device__ __forceinline__ short8 load_wfrag(const float* __restrict__ Whh,
                                             const float* __restrict__ Wih,
                                             int row, int k) {
    const float* p = (k < Hh) ? (Whh + row * Hh + k) : (Wih + row * Ii + (k - Hh));
    f32x4 lo = *(const f32x4*)p;
    f32x4 hi = *(const f32x4*)(p + 4);
    return pack_bf8(lo, hi);
}

__device__ __forceinline__ int ldsa(int row, int kbyte) {
    // XOR swizzle: spreads the stride-1280B rows across banks for ds_read_b128
    return (row * 1280 + kbyte) ^ ((row & 7) << 4);
}

__device__ __forceinline__ float sigm(float v)  { return 1.f / (1.f + __expf(-v)); }
__device__ __forceinline__ float tanhf_(float v){ return 1.f - 2.f / (__expf(2.f * v) + 1.f); }

__global__ void zero_ctr(int* c, int n) {
    int i = blockIdx.x * blockDim.x + threadIdx.x;
    if (i < n) c[i] = 0;
}

__global__ __launch_bounds__(256, 1)
void gru_persist(const float* __restrict__ x,   const float* __restrict__ Wih,
                 const float* __restrict__ Whh, const float* __restrict__ bih,
                 const float* __restrict__ bhh, const float* __restrict__ Wlin,
                 const float* __restrict__ blin, float* __restrict__ out,
                 float* __restrict__ hbuf, int* __restrict__ ctr)
{
    __shared__ __align__(16) unsigned char lA[16 * 1280];   // [16 rows][640 bf16]

    const int wg   = blockIdx.x;
    const int tid  = threadIdx.x;
    const int lane = tid & 63;
    const int w    = tid >> 6;          // wave 0..3
    // Keep a group's 8 slices on nearby CUs (perf heuristic only; correctness
    // does not depend on placement — all sync is agent-scope at the LLC).
    const int xcd8 = wg & 7, lg = (wg >> 3) & 3, sl = wg >> 5;
    const int g   = xcd8 * 4 + lg;      // group 0..31
    const int b0  = g * BM;
    const int jw  = sl * 64 + w * 16;   // this wave's 16 h-columns
    const int col16 = lane & 15;
    const int kg8   = (lane >> 4) * 8;  // k sub-offset within a K=32 tile
    const int colg  = jw + col16;       // global h-column this lane owns

    // biases (per-lane, per its column)
    const float br  = bih[colg] + bhh[colg];
    const float bz  = bih[Hh + colg] + bhh[Hh + colg];
    const float bxn = bih[2 * Hh + colg];
    const float bhn = bhh[2 * Hh + colg];

    // ---- load weight B-fragments once into registers (persistent) ----
    short8 wR[20], wZ[20], wN[20];
#pragma unroll
    for (int kt = 0; kt < 20; ++kt) {
        int k = kt * 32 + kg8;
        wR[kt] = load_wfrag(Whh, Wih, colg, k);
        wZ[kt] = load_wfrag(Whh, Wih, Hh + colg, k);
        wN[kt] = load_wfrag(Whh, Wih, 2 * Hh + colg, k);
    }

    float* hb0 = hbuf;
    float* hb1 = hbuf + Bdim * Hh;
    int* myctr = ctr + g * Tt;

    f32x4 hreg = {0.f, 0.f, 0.f, 0.f};  // own h tile, exact fp32 carry

    // x prefetch for t=0 (plain compiler-tracked loads)
    const int xrow0 = tid >> 5,         xc40 = tid & 31;
    const int xrow1 = (256 + tid) >> 5, xc41 = (256 + tid) & 31;
    f32x4 xr0 = *(const f32x4*)(x + ((size_t)(b0 + xrow0) * Tt + 0) * Ii + xc40 * 4);
    f32x4 xr1 = *(const f32x4*)(x + ((size_t)(b0 + xrow1) * Tt + 0) * Ii + xc41 * 4);

#pragma unroll 1
    for (int t = 0; t < Tt; ++t) {
        const int pin = t & 1;
        float*       hout = pin ? hb0 : hb1;
        const float* hin  = pin ? hb1 : hb0;

        // ---- stage x_t (prefetched regs) -> bf16 LDS cols [512,640) ----
        {
            unsigned long long pk0 = (unsigned long long)f2bf(xr0[0])
                                   | ((unsigned long long)f2bf(xr0[1]) << 16)
                                   | ((unsigned long long)f2bf(xr0[2]) << 32)
                                   | ((unsigned long long)f2bf(xr0[3]) << 48);
            *(unsigned long long*)(lA + ldsa(xrow0, 1024 + xc40 * 8)) = pk0;
            unsigned long long pk1 = (unsigned long long)f2bf(xr1[0])
                                   | ((unsigned long long)f2bf(xr1[1]) << 16)
                                   | ((unsigned long long)f2bf(xr1[2]) << 32)
                                   | ((unsigned long long)f2bf(xr1[3]) << 48);
            *(unsigned long long*)(lA + ldsa(xrow1, 1024 + xc41 * 8)) = pk1;
        }
        __syncthreads();

        // prefetch x_{t+1} (overlaps poll + panel load + MFMAs)
        if (t + 1 < Tt) {
            xr0 = *(const f32x4*)(x + ((size_t)(b0 + xrow0) * Tt + (t + 1)) * Ii + xc40 * 4);
            xr1 = *(const f32x4*)(x + ((size_t)(b0 + xrow1) * Tt + (t + 1)) * Ii + xc41 * 4);
        }

        f32x4 accR = {0,0,0,0}, accZ = {0,0,0,0}, accNH = {0,0,0,0}, accNX = {0,0,0,0};

        // ---- x-part MFMAs (independent of h -> overlap with the flag wait) ----
#pragma unroll
        for (int kt = 16; kt < 20; ++kt) {
            short8 a = *(const short8*)(lA + ldsa(col16, (kt * 32 + kg8) * 2));
            accR  = __builtin_amdgcn_mfma_f32_16x16x32_bf16(a, wR[kt], accR, 0, 0, 0);
            accZ  = __builtin_amdgcn_mfma_f32_16x16x32_bf16(a, wZ[kt], accZ, 0, 0, 0);
            accNX = __builtin_amdgcn_mfma_f32_16x16x32_bf16(a, wN[kt], accNX, 0, 0, 0);
        }

        if (t > 0) {
            // ---- group barrier: relaxed poll, bounded so a protocol bug
            //      degrades to fast wrong-answer instead of a harness timeout ----
            if (tid == 0) {
                int spin = 0;
                while (__hip_atomic_load(myctr + (t - 1), __ATOMIC_RELAXED,
                                         __HIP_MEMORY_SCOPE_AGENT) < NSL
                       && spin < (1 << 20)) {
                    ++spin;
                    __builtin_amdgcn_s_sleep(1);
                }
            }
            __syncthreads();

            // ---- stage h panel (16 rows x 512 f32 = 32KB): issue all 16
            //      8B agent-scope loads first (one vmcnt batch), then convert ----
            unsigned long long vv[16];
#pragma unroll
            for (int it = 0; it < 16; ++it) {
                int idx = it * 256 + tid;      // [0,4096): 8B chunks
                int row = idx >> 8;            // 256 chunks per row
                int c2  = idx & 255;
                vv[it] = __hip_atomic_load(
                    (const unsigned long long*)(hin + (size_t)(b0 + row) * Hh + c2 * 2),
                    __ATOMIC_RELAXED, __HIP_MEMORY_SCOPE_AGENT);
            }
#pragma unroll
            for (int it = 0; it < 16; ++it) {
                int idx = it * 256 + tid;
                int row = idx >> 8;
                int c2  = idx & 255;
                float f0 = __builtin_bit_cast(float, (unsigned)(vv[it] & 0xffffffffu));
                float f1 = __builtin_bit_cast(float, (unsigned)(vv[it] >> 32));
                unsigned pk = (unsigned)f2bf(f0) | ((unsigned)f2bf(f1) << 16);
                *(unsigned*)(lA + ldsa(row, c2 * 4)) = pk;
            }
            __syncthreads();

            // ---- h-part MFMAs ----
#pragma unroll
            for (int kt = 0; kt < 16; ++kt) {
                short8 a = *(const short8*)(lA + ldsa(col16, (kt * 32 + kg8) * 2));
                accR  = __builtin_amdgcn_mfma_f32_16x16x32_bf16(a, wR[kt], accR, 0, 0, 0);
                accZ  = __builtin_amdgcn_mfma_f32_16x16x32_bf16(a, wZ[kt], accZ, 0, 0, 0);
                accNH = __builtin_amdgcn_mfma_f32_16x16x32_bf16(a, wN[kt], accNH, 0, 0, 0);
            }
        }

        // ---- gates + state update (C/D layout: col=lane&15, row=(lane>>4)*4+i) ----
#pragma unroll
        for (int i = 0; i < 4; ++i) {
            int row = (lane >> 4) * 4 + i;
            float hp = hreg[i];
            float r  = sigm(accR[i] + br);
            float z  = sigm(accZ[i] + bz);
            float n  = tanhf_(accNX[i] + bxn + r * (accNH[i] + bhn));
            float hv = (1.f - z) * n + z * hp;
            hreg[i] = hv;
            // agent-scope relaxed store: write-through to the coherent LLC
            __hip_atomic_store(hout + (size_t)(b0 + row) * Hh + colg, hv,
                               __ATOMIC_RELAXED, __HIP_MEMORY_SCOPE_AGENT);
        }
        // per-wave drain: stores acked at the coherence point before the flag.
        // (plain waitcnt-to-zero; compiler's own later waits remain conservative)
        asm volatile("s_waitcnt vmcnt(0)" ::: "memory");
        __syncthreads();
        if (tid == 0)
            __hip_atomic_fetch_add(myctr + t, 1, __ATOMIC_RELAXED,
                                   __HIP_MEMORY_SCOPE_AGENT);
    }

    // ---- final linear: slice-0 WG of each group computes out[b0..b0+15] ----
    if (sl == 0) {
        if (tid == 0) {
            int spin = 0;
            while (__hip_atomic_load(myctr + (Tt - 1), __ATOMIC_RELAXED,
                                     __HIP_MEMORY_SCOPE_AGENT) < NSL
                   && spin < (1 << 20)) {
                ++spin;
                __builtin_amdgcn_s_sleep(1);
            }
        }
        __syncthreads();
        const float* hf = hb0;   // T even -> final state in buffer 0
        const float bl = blin[0];
        for (int rr = w; rr < BM; rr += 4) {
            int b = b0 + rr;
            float sum = 0.f;
#pragma unroll
            for (int c = 0; c < 4; ++c) {
                int cc = lane * 8 + c * 2;
                unsigned long long vv = __hip_atomic_load(
                    (const unsigned long long*)(hf + (size_t)b * Hh + cc),
                    __ATOMIC_RELAXED, __HIP_MEMORY_SCOPE_AGENT);
                float f0 = __builtin_bit_cast(float, (unsigned)(vv & 0xffffffffu));
                float f1 = __builtin_bit_cast(float, (unsigned)(vv >> 32));
                sum += f0 * Wlin[cc] + f1 * Wlin[cc + 1];
            }
#pragma unroll
            for (int off = 32; off; off >>= 1) sum += __shfl_xor(sum, off);
            if (lane == 0) out[b] = sum + bl;
        }
    }
}

extern "C" void kernel_launch(void* const* d_in, const int* in_sizes, int n_in,
                              void* d_out, int out_size, void* d_ws, size_t ws_size,
                              hipStream_t stream) {
    const float* x    = (const float*)d_in[0];
    const float* Wih  = (const float*)d_in[1];
    const float* Whh  = (const float*)d_in[2];
    const float* bih  = (const float*)d_in[3];
    const float* bhh  = (const float*)d_in[4];
    const float* Wlin = (const float*)d_in[5];
    const float* blin = (const float*)d_in[6];
    float* out  = (float*)d_out;

    float* hbuf = (float*)d_ws;                                        // 2 MB
    int*   ctr  = (int*)((char*)d_ws + 2ull * Bdim * Hh * sizeof(float));

    zero_ctr<<<(NGRP * Tt + 255) / 256, 256, 0, stream>>>(ctr, NGRP * Tt);
    gru_persist<<<256, 256, 0, stream>>>(x, Wih, Whh, bih, bhh, Wlin, blin, out,
                                         hbuf, ctr);
}